// Round 4
// baseline (117.934 us; speedup 1.0000x reference)
//
#include <hip/hip_runtime.h>
#include <math.h>

namespace {

constexpr int B_ = 4;
constexpr int N_ = 512;
constexpr int D_ = 256;
constexpr int L_ = 128;
constexpr int TI = 8;      // i-rows per block in phase B
constexpr int NBLK = 256;  // total blocks; worst-case residency 512 >= 256

// One fused kernel: Phase A (projection, a-prescaled, transposed xs) ->
// grid barrier -> Phase B (L1-dist + mask + leaky-relu + row softmax).
__global__ __launch_bounds__(512, 2) void fused_kernel(
    const float* __restrict__ x, const float* __restrict__ adj,
    const int* __restrict__ box_num, const float* __restrict__ W,
    const float* __restrict__ a, float* __restrict__ xs,
    unsigned int* __restrict__ bar_cnt, float* __restrict__ out) {
  __shared__ __align__(16) float smem[65 * 64 * 4];  // 66,560 B

  const int t = threadIdx.x;
  const int blk = blockIdx.x;
  const int b = blk >> 6;

  // ---------------- Phase A: xs[b][l][n] = a[l] * dot(x[b][n], W[l]) -------
  {
    const int tile = blk & 63;
    const int l0 = (tile >> 3) * 16;  // 16 l per block
    const int n0 = (tile & 7) * 64;   // 64 n per block

    float4* lds4 = reinterpret_cast<float4*>(smem);
    // stage x[b][n0..n0+64][:] -> LDS transposed [d4][n], pad 65
    const float4* __restrict__ xsrc =
        reinterpret_cast<const float4*>(x + ((size_t)(b * N_ + n0)) * D_);
#pragma unroll
    for (int k = 0; k < 8; ++k) {
      const int idx = t + k * 512;  // 0..4095, coalesced global read
      const int row = idx >> 6;     // local n
      const int d4 = idx & 63;
      lds4[d4 * 65 + row] = xsrc[idx];
    }
    __syncthreads();

    const int lw = __builtin_amdgcn_readfirstlane(t >> 6);  // wave id 0..7
    const int j = t & 63;                                   // local n
    const int l_ = l0 + lw * 2;
    const float4* __restrict__ W4 = reinterpret_cast<const float4*>(W);
    float acc0 = 0.f, acc1 = 0.f;
#pragma unroll 8
    for (int d4 = 0; d4 < 64; ++d4) {
      const float4 xv = lds4[d4 * 65 + j];  // conflict-free b128
      const float4 w0 = W4[(size_t)l_ * 64 + d4];        // uniform -> s_load
      const float4 w1 = W4[(size_t)(l_ + 1) * 64 + d4];  // uniform -> s_load
      acc0 += xv.x * w0.x + xv.y * w0.y + xv.z * w0.z + xv.w * w0.w;
      acc1 += xv.x * w1.x + xv.y * w1.y + xv.z * w1.z + xv.w * w1.w;
    }
    xs[((size_t)(b * L_ + l_ + 0)) * N_ + n0 + j] = acc0 * a[l_ + 0];
    xs[((size_t)(b * L_ + l_ + 1)) * N_ + n0 + j] = acc1 * a[l_ + 1];
  }

  // ---------------- grid barrier (all 256 blocks resident by capacity) -----
  __threadfence();  // release xs writes (agent scope)
  __syncthreads();
  if (t == 0) {
    __hip_atomic_fetch_add(bar_cnt, 1u, __ATOMIC_ACQ_REL,
                           __HIP_MEMORY_SCOPE_AGENT);
    while (__hip_atomic_load(bar_cnt, __ATOMIC_ACQUIRE,
                             __HIP_MEMORY_SCOPE_AGENT) < (unsigned)NBLK) {
      __builtin_amdgcn_s_sleep(1);
    }
  }
  __syncthreads();
  __threadfence();  // acquire: invalidate stale L1/L2 before xs reads

  // ---------------- Phase B: dist + softmax --------------------------------
  const int jcol = t;
  const int i0 = (blk & 63) * TI;
  const int bn = box_num[b];
  const float* __restrict__ xs_b = xs + (size_t)b * L_ * N_;

  float* xi_l = smem;  // L_*TI = 1024 floats
  float(*red)[TI] = reinterpret_cast<float(*)[TI]>(smem + 1024);  // 8x8
  float* sa_l = smem + 1024 + 64;
  float* rmax_s = sa_l + 2;
  float* rsinv_s = rmax_s + TI;

  // stage i-rows: 1024 elems, 2 per thread; idx -> (l = idx>>3, r = idx&7)
#pragma unroll
  for (int s = 0; s < 2; ++s) {
    const int idx = t + s * 512;
    xi_l[idx] = xs_b[(idx >> 3) * N_ + i0 + (idx & 7)];
  }

  // sum(a) prologue
  {
    float sa = (t < L_) ? a[t] : 0.f;
#pragma unroll
    for (int off = 1; off < 64; off <<= 1) sa += __shfl_xor(sa, off);
    if (t == 0) sa_l[0] = sa;
    if (t == 64) sa_l[1] = sa;
  }
  __syncthreads();
  const float sum_a = sa_l[0] + sa_l[1];

  float acc[TI];
#pragma unroll
  for (int r = 0; r < TI; ++r) acc[r] = 0.f;

  const float4* __restrict__ xi4 = reinterpret_cast<const float4*>(xi_l);
#pragma unroll 4
  for (int l = 0; l < L_; ++l) {
    const float xj = xs_b[l * N_ + jcol];  // coalesced, L2-resident
    const float4 xiA = xi4[2 * l];         // broadcast ds_read_b128
    const float4 xiB = xi4[2 * l + 1];
    acc[0] += fabsf(xiA.x - xj);
    acc[1] += fabsf(xiA.y - xj);
    acc[2] += fabsf(xiA.z - xj);
    acc[3] += fabsf(xiA.w - xj);
    acc[4] += fabsf(xiB.x - xj);
    acc[5] += fabsf(xiB.y - xj);
    acc[6] += fabsf(xiB.z - xj);
    acc[7] += fabsf(xiB.w - xj);
  }

  const bool vj = jcol < bn;
  float val[TI];
#pragma unroll
  for (int r = 0; r < TI; ++r) {
    const bool vi = (i0 + r) < bn;
    const float d = acc[r] - ((vi && vj) ? 0.f : sum_a);  // + mask*sum(a)
    val[r] = d >= 0.f ? d : 0.01f * d;                    // leaky_relu
  }

  const int lane = t & 63;
  const int wid = t >> 6;

  // ---- row max over 512 j ----
  {
    float wm[TI];
#pragma unroll
    for (int r = 0; r < TI; ++r) {
      float m = val[r];
#pragma unroll
      for (int off = 1; off < 64; off <<= 1) m = fmaxf(m, __shfl_xor(m, off));
      wm[r] = m;
    }
    if (lane == 0) {
#pragma unroll
      for (int r = 0; r < TI; ++r) red[wid][r] = wm[r];
    }
  }
  __syncthreads();
  if (t < TI) {
    float m = red[0][t];
#pragma unroll
    for (int w = 1; w < 8; ++w) m = fmaxf(m, red[w][t]);
    rmax_s[t] = m;
  }
  __syncthreads();

  float e[TI];
  const float* __restrict__ adjp = adj + ((size_t)(b * N_ + i0)) * N_ + jcol;
#pragma unroll
  for (int r = 0; r < TI; ++r) {
    e[r] = adjp[(size_t)r * N_] * expf(val[r] - rmax_s[r]);
  }

  // ---- row sum over 512 j ----
  {
    float wsum[TI];
#pragma unroll
    for (int r = 0; r < TI; ++r) {
      float s = e[r];
#pragma unroll
      for (int off = 1; off < 64; off <<= 1) s += __shfl_xor(s, off);
      wsum[r] = s;
    }
    if (lane == 0) {
#pragma unroll
      for (int r = 0; r < TI; ++r) red[wid][r] = wsum[r];
    }
  }
  __syncthreads();
  if (t < TI) {
    float s = red[0][t];
#pragma unroll
    for (int w = 1; w < 8; ++w) s += red[w][t];
    rsinv_s[t] = 1.0f / s;
  }
  __syncthreads();

  float* __restrict__ op = out + ((size_t)(b * N_ + i0)) * N_ + jcol;
#pragma unroll
  for (int r = 0; r < TI; ++r) {
    op[(size_t)r * N_] = e[r] * rsinv_s[r] + 1e-10f;
  }
}

}  // namespace

extern "C" void kernel_launch(void* const* d_in, const int* in_sizes, int n_in,
                              void* d_out, int out_size, void* d_ws,
                              size_t ws_size, hipStream_t stream) {
  (void)in_sizes;
  (void)n_in;
  (void)out_size;
  (void)ws_size;
  const float* x = (const float*)d_in[0];    // (B,N,D) f32
  const float* adj = (const float*)d_in[1];  // (B,N,N) f32
  const int* box_num = (const int*)d_in[2];  // (B,1) int32
  const float* W = (const float*)d_in[3];    // (L,D) f32
  const float* a = (const float*)d_in[4];    // (L,) f32
  float* out = (float*)d_out;                // (B,N,N) f32

  float* xs = (float*)d_ws;  // B*L*N floats = 1 MB
  unsigned int* bar_cnt =
      (unsigned int*)((char*)d_ws + (size_t)B_ * L_ * N_ * sizeof(float));

  // zero the barrier counter each call (graph-capturable memset node)
  hipMemsetAsync(bar_cnt, 0, sizeof(unsigned int), stream);

  fused_kernel<<<NBLK, 512, 0, stream>>>(x, adj, box_num, W, a, xs, bar_cnt,
                                         out);
}